// Round 10
// baseline (197.501 us; speedup 1.0000x reference)
//
#include <hip/hip_runtime.h>
#include <hip/hip_bf16.h>
#include <math.h>

// N_MAX_L = [22,19,16,13], offsets [0,22,41,57], N_TOTAL=70
// W1: (4,4,22,32)  W2/W3: (4,4,32,32)  W4: (4,4,32,22)
#define BLK 256
#define BX 128
#define TSL 24608  // padded per-l table slice: 1024*24 + 32 floats

typedef __attribute__((ext_vector_type(8))) short short8;
typedef __attribute__((ext_vector_type(4))) float f32x4;

union Frag {
  short8 s;
  unsigned int u[4];
};

// RNE pack of two f32 -> packed bf16x2 (low half = a). Proven in rounds 5-8.
__device__ __forceinline__ unsigned int pack_pair(float a, float b) {
  __hip_bfloat162 h2 = __float22bfloat162_rn(float2{a, b});
  return *reinterpret_cast<unsigned int*>(&h2);
}

// hi/lo split: hi = RNE-bf16 pair, lo = RNE-bf16 of residuals
__device__ __forceinline__ void split_pair(float a, float b, unsigned int& hi,
                                           unsigned int& lo) {
  hi = pack_pair(a, b);
  const float ra = a - __uint_as_float(hi << 16);
  const float rb = b - __uint_as_float(hi & 0xFFFF0000u);
  lo = pack_pair(ra, rb);
}

// ---------------- histogram / prefix / compaction ----------------

__global__ void k_zero(int* __restrict__ cnt) {
  if (threadIdx.x < 4) cnt[threadIdx.x] = 0;
}

__global__ void __launch_bounds__(BLK) k_hist(const int* __restrict__ spc, int n,
                                              int* __restrict__ cnt) {
  __shared__ int h[4];
  if (threadIdx.x < 4) h[threadIdx.x] = 0;
  __syncthreads();
  const int i = blockIdx.x * BLK + threadIdx.x;
  if (i < n) atomicAdd(&h[spc[i]], 1);
  __syncthreads();
  if (threadIdx.x < 4) atomicAdd(&cnt[threadIdx.x], h[threadIdx.x]);
}

__global__ void k_prefix(const int* __restrict__ cnt, int* __restrict__ cnt2,
                         int* __restrict__ csum) {
  if (threadIdx.x == 0) {
    int a = 0;
#pragma unroll
    for (int s = 0; s < 4; s++) {
      csum[s] = a;
      cnt2[s] = a;
      a += cnt[s];
    }
  }
}

__global__ void __launch_bounds__(BLK) k_compact(const int* __restrict__ spc,
                                                 const float* __restrict__ r, int n,
                                                 int* __restrict__ cnt2,
                                                 int* __restrict__ inv,
                                                 float* __restrict__ fracs,
                                                 int* __restrict__ toffA,
                                                 int* __restrict__ perm) {
  __shared__ int wcnt[4][4];
  __shared__ int wbase[4][4];
  const int tid = threadIdx.x;
  const int i = blockIdx.x * BLK + tid;
  const int lane = tid & 63;
  const int w = tid >> 6;
  const int s = (i < n) ? spc[i] : -1;
  const float rr = (i < n) ? r[i] : 0.f;

  int rank = 0;
#pragma unroll
  for (int sp = 0; sp < 4; sp++) {
    unsigned long long m = __ballot(s == sp);
    if (lane == 0) wcnt[w][sp] = __popcll(m);
    if (s == sp) rank = __popcll(m & ((1ULL << lane) - 1ULL));
  }
  __syncthreads();
  if (tid < 4) {
    const int c0 = wcnt[0][tid], c1 = wcnt[1][tid], c2 = wcnt[2][tid], c3 = wcnt[3][tid];
    const int b = atomicAdd(&cnt2[tid], c0 + c1 + c2 + c3);
    wbase[0][tid] = b;
    wbase[1][tid] = b + c0;
    wbase[2][tid] = b + c0 + c1;
    wbase[3][tid] = b + c0 + c1 + c2;
  }
  __syncthreads();
  if (s >= 0) {
    const int sp = wbase[w][s] + rank;  // tight index = csum[s] + pos
    const float xi = rr * (1023.0f / 5.0f);
    int idx = (int)floorf(xi);
    idx = idx < 0 ? 0 : (idx > 1022 ? 1022 : idx);
    inv[i] = sp;
    fracs[sp] = xi - (float)idx;
    toffA[sp] = idx * 96;  // table row = 24 f32 = 96 B
    perm[sp] = i;          // only used by DIRECT fallback
  }
}

// ---------------- padded table staging ----------------

__global__ void __launch_bounds__(256) k_table(const float* __restrict__ tbl,
                                               float* __restrict__ wt) {
  const int t = blockIdx.x * 256 + threadIdx.x;
  if (t < 4 * 1024 * 24) {
    const int l = t / (1024 * 24);
    const int rem = t - l * (1024 * 24);
    const int idx = rem / 24;
    const int j = rem - idx * 24;
    const int off = (l == 0) ? 0 : (l == 1) ? 22 : (l == 2) ? 41 : 57;
    const int nl = (l == 0) ? 22 : (l == 1) ? 19 : (l == 2) ? 16 : 13;
    const float v = (j < nl) ? tbl[idx * 70 + off + j] : 0.f;
    wt[l * TSL + idx * 24 + j] = v;
  }
  if (t < 4 * 32) {
    const int l = t >> 5, j = t & 31;
    wt[l * TSL + 1024 * 24 + j] = 0.f;
  }
}

// ---------------- MFMA compute ----------------

__device__ __forceinline__ void layer_hl(const Frag* A, const Frag& bh,
                                         const Frag& bl, f32x4& d0, f32x4& d1) {
  f32x4 z = {0.f, 0.f, 0.f, 0.f};
  d0 = __builtin_amdgcn_mfma_f32_16x16x32_bf16(A[0].s, bl.s, z, 0, 0, 0);
  d0 = __builtin_amdgcn_mfma_f32_16x16x32_bf16(A[0].s, bh.s, d0, 0, 0, 0);
  d1 = __builtin_amdgcn_mfma_f32_16x16x32_bf16(A[1].s, bl.s, z, 0, 0, 0);
  d1 = __builtin_amdgcn_mfma_f32_16x16x32_bf16(A[1].s, bh.s, d1, 0, 0, 0);
}

__device__ __forceinline__ void layer_h(const Frag* A, const Frag& bh, f32x4& d0,
                                        f32x4& d1) {
  f32x4 z = {0.f, 0.f, 0.f, 0.f};
  d0 = __builtin_amdgcn_mfma_f32_16x16x32_bf16(A[0].s, bh.s, z, 0, 0, 0);
  d1 = __builtin_amdgcn_mfma_f32_16x16x32_bf16(A[1].s, bh.s, z, 0, 0, 0);
}

__device__ __forceinline__ f32x4 silu4(f32x4 v) {
#pragma unroll
  for (int i = 0; i < 4; i++) v[i] = __fdividef(v[i], 1.0f + __expf(-v[i]));
  return v;
}

struct GD {
  f32x4 a0, a1, b0, b1;
  float frac;
  int e;
  int valid;
};

// 0-hop gather: frac/toff precomputed streams + table rows (L2/L3).
template <bool DIRECT>
__device__ __forceinline__ GD do_gather(const float* __restrict__ fracs,
                                        const int* __restrict__ toffA,
                                        const int* __restrict__ perm,
                                        const char* __restrict__ tbB, int sp0,
                                        int ei, int count) {
  GD gd;
  gd.valid = ei < count;
  const int spi = sp0 + (gd.valid ? ei : 0);
  gd.frac = fracs[spi];
  const int to = toffA[spi];
  if (DIRECT) gd.e = perm[spi]; else gd.e = 0;
  const char* p = tbB + to;
  gd.a0 = *(const f32x4*)(p);
  gd.a1 = *(const f32x4*)(p + 16);
  gd.b0 = *(const f32x4*)(p + 96);
  gd.b1 = *(const f32x4*)(p + 112);
  return gd;
}

template <int L, int NL, int OFF, bool DIRECT>
__device__ void body(const float* __restrict__ fracs, const int* __restrict__ toffA,
                     const float* __restrict__ wt, const float* __restrict__ W1,
                     const float* __restrict__ W2, const float* __restrict__ W3,
                     const float* __restrict__ W4, float* __restrict__ out,
                     const int* __restrict__ cnt, const int* __restrict__ csum,
                     const int* __restrict__ perm, unsigned short* __restrict__ tmp16,
                     int n) {
  const int s = blockIdx.y & 3;
  const int count = cnt[s];
  if (count == 0) return;
  const int sp0 = csum[s];

  const int lane = threadIdx.x & 63;
  const int w = threadIdx.x >> 6;
  const int c = lane & 15;  // edge column within tile
  const int g = lane >> 4;  // k-group

  const float* __restrict__ w1 = W1 + (size_t)(L * 4 + s) * (22 * 32);
  const float* __restrict__ w2 = W2 + (size_t)(L * 4 + s) * (32 * 32);
  const float* __restrict__ w3 = W3 + (size_t)(L * 4 + s) * (32 * 32);
  const float* __restrict__ w4 = W4 + (size_t)(L * 4 + s) * (32 * 22);

  // A-frags (bf16-RNE, hi only): W1 standard k=8g+d; W2/W3/W4 permuted
  // k'(g,d) = (d<4 ? 4g+d : 16+4g+d-4) so the previous layer's D-register
  // layout feeds the next MFMA directly (no transpose, no LDS).
  Frag A1[2], A2[2], A3[2], A4[2];
#pragma unroll
  for (int jt = 0; jt < 2; jt++) {
    const int j = jt * 16 + c;
#pragma unroll
    for (int p = 0; p < 4; p++) {
      const int k0 = 8 * g + 2 * p, k1 = k0 + 1;
      const float a = (k0 < NL) ? w1[k0 * 32 + j] : 0.f;
      const float b = (k1 < NL) ? w1[k1 * 32 + j] : 0.f;
      A1[jt].u[p] = pack_pair(a, b);
      const int kp0 = (p < 2) ? (4 * g + 2 * p) : (16 + 4 * g + 2 * (p - 2));
      const int kp1 = kp0 + 1;
      A2[jt].u[p] = pack_pair(w2[kp0 * 32 + j], w2[kp1 * 32 + j]);
      A3[jt].u[p] = pack_pair(w3[kp0 * 32 + j], w3[kp1 * 32 + j]);
      A4[jt].u[p] = pack_pair((j < NL) ? w4[kp0 * 22 + j] : 0.f,
                              (j < NL) ? w4[kp1 * 22 + j] : 0.f);
    }
  }

  const char* __restrict__ tbB = (const char*)(wt + L * TSL + 8 * g);
  // per-l tmp base (bytes): l0:0, l1:48n, l2:96n, l3:128n ; row = 48/48/32/32 B
  constexpr int ROWB = (L < 2) ? 48 : 32;
  char* __restrict__ tmpB =
      (char*)tmp16 + (size_t)n * (L == 0 ? 0 : L == 1 ? 48 : L == 2 ? 96 : 128);

  const int stride = gridDim.x * 64;
  int eb = blockIdx.x * 64 + w * 16;
  GD cur = do_gather<DIRECT>(fracs, toffA, perm, tbB, sp0, eb + c, count);

  for (; eb < count; eb += stride) {
    GD nxt = do_gather<DIRECT>(fracs, toffA, perm, tbB, sp0, eb + stride + c, count);

    // ---- layer-1 B frags (standard k = 8g+d; pads are zero), hi/lo split ----
    Frag bh, bl;
    {
      float x[8];
#pragma unroll
      for (int d = 0; d < 4; d++) {
        x[d] = cur.a0[d] + cur.frac * (cur.b0[d] - cur.a0[d]);
        x[d + 4] = cur.a1[d] + cur.frac * (cur.b1[d] - cur.a1[d]);
      }
      split_pair(x[0], x[1], bh.u[0], bl.u[0]);
      split_pair(x[2], x[3], bh.u[1], bl.u[1]);
      split_pair(x[4], x[5], bh.u[2], bl.u[2]);
      split_pair(x[6], x[7], bh.u[3], bl.u[3]);
    }

    f32x4 d0, d1;
    layer_hl(A1, bh, bl, d0, d1);

    // ---- transitions: silu -> bf16 repack (k'-mapping) -> next layer ----
#pragma unroll
    for (int t = 0; t < 3; t++) {
      d0 = silu4(d0);
      d1 = silu4(d1);
      bh.u[0] = pack_pair(d0[0], d0[1]);
      bh.u[1] = pack_pair(d0[2], d0[3]);
      bh.u[2] = pack_pair(d1[0], d1[1]);
      bh.u[3] = pack_pair(d1[2], d1[3]);
      if (t == 0) layer_h(A2, bh, d0, d1);
      else if (t == 1) layer_h(A3, bh, d0, d1);
      else layer_h(A4, bh, d0, d1);
    }

    if (!DIRECT) {
      // ---- dense bf16 epilogue: row sp = sp0+ei, features in order ----
      // d0 -> features 4g..4g+3 (byte 8g), d1 -> 16+4g..19+4g (byte 32+8g)
      if (cur.valid) {
        const size_t ro = (size_t)(sp0 + eb + c) * ROWB;
        const unsigned int u0 = pack_pair(d0[0], d0[1]);
        const unsigned int u1 = pack_pair(d0[2], d0[3]);
        *(uint2*)(tmpB + ro + 8 * g) = make_uint2(u0, u1);
        if (NL > 16 && g < 2) {
          const unsigned int u2 = pack_pair(d1[0], d1[1]);
          const unsigned int u3 = pack_pair(d1[2], d1[3]);
          *(uint2*)(tmpB + ro + 32 + 8 * g) = make_uint2(u2, u3);
        }
      }
    } else {
      // fallback: scattered f32 stores (ws too small for tmp)
      float* __restrict__ o = out + (size_t)cur.e * 70 + OFF;
#pragma unroll
      for (int i2 = 0; i2 < 4; i2++) {
        const int j0 = 4 * g + i2;
        if (cur.valid && j0 < NL) o[j0] = d0[i2];
        const int j1 = 16 + 4 * g + i2;
        if (cur.valid && j1 < NL) o[j1] = d1[i2];
      }
    }

    cur = nxt;
  }
}

template <bool DIRECT>
__global__ void __launch_bounds__(BLK) rb_mfma(const float* __restrict__ fracs,
                                               const int* __restrict__ toffA,
                                               const float* __restrict__ wt,
                                               const float* __restrict__ W1,
                                               const float* __restrict__ W2,
                                               const float* __restrict__ W3,
                                               const float* __restrict__ W4,
                                               float* __restrict__ out,
                                               const int* __restrict__ cnt,
                                               const int* __restrict__ csum,
                                               const int* __restrict__ perm,
                                               unsigned short* __restrict__ tmp16,
                                               int n) {
  switch (blockIdx.y >> 2) {
    case 0: body<0, 22, 0, DIRECT>(fracs, toffA, wt, W1, W2, W3, W4, out, cnt, csum, perm, tmp16, n); break;
    case 1: body<1, 19, 22, DIRECT>(fracs, toffA, wt, W1, W2, W3, W4, out, cnt, csum, perm, tmp16, n); break;
    case 2: body<2, 16, 41, DIRECT>(fracs, toffA, wt, W1, W2, W3, W4, out, cnt, csum, perm, tmp16, n); break;
    default: body<3, 13, 57, DIRECT>(fracs, toffA, wt, W1, W2, W3, W4, out, cnt, csum, perm, tmp16, n); break;
  }
}

// ---------------- natural-order streaming scatter ----------------

__global__ void __launch_bounds__(256) k_scatter(const unsigned short* __restrict__ tmp16,
                                                 const int* __restrict__ inv,
                                                 float* __restrict__ out, int n) {
  __shared__ int sinv[64];
  const int i0 = blockIdx.x * 64;
  if (threadIdx.x < 64) {
    const int i = i0 + threadIdx.x;
    sinv[threadIdx.x] = (i < n) ? inv[i] : 0;
  }
  __syncthreads();
  const long n24 = (long)n * 24;
  for (int t = threadIdx.x; t < 64 * 70; t += 256) {
    const int il = t / 70;
    const int f = t - il * 70;
    const int i = i0 + il;
    if (i >= n) continue;
    const long sp = (long)sinv[il];
    long hidx;
    if (f < 22) hidx = sp * 24 + f;
    else if (f < 41) hidx = n24 + sp * 24 + (f - 22);
    else if (f < 57) hidx = 2 * n24 + sp * 16 + (f - 41);
    else hidx = 2 * n24 + (long)n * 16 + sp * 16 + (f - 57);
    const unsigned int h = tmp16[hidx];
    out[(size_t)i0 * 70 + t] = __uint_as_float(h << 16);
  }
}

extern "C" void kernel_launch(void* const* d_in, const int* in_sizes, int n_in,
                              void* d_out, int out_size, void* d_ws, size_t ws_size,
                              hipStream_t stream) {
  const float* r = (const float*)d_in[0];
  const int* spc = (const int*)d_in[1];
  const float* tbl = (const float*)d_in[2];
  const float* W1 = (const float*)d_in[3];
  const float* W2 = (const float*)d_in[4];
  const float* W3 = (const float*)d_in[5];
  const float* W4 = (const float*)d_in[6];
  float* out = (float*)d_out;
  const int n = in_sizes[0];

  int* cnt = (int*)d_ws;        // [0..3]
  int* cnt2 = cnt + 4;          // [4..7] atomic bases
  int* csum = cnt + 8;          // [8..11]
  int* inv = cnt + 64;          // n ints
  float* fracs = (float*)(inv + n);
  int* toffA = (int*)(fracs + n);
  int* perm = toffA + n;
  float* wtbl = (float*)(perm + n);
  unsigned short* tmp16 = (unsigned short*)(wtbl + 4 * TSL);
  const size_t need = (size_t)((char*)(tmp16 + (size_t)80 * n) - (char*)d_ws);
  const bool direct = ws_size < need;

  hipLaunchKernelGGL(k_zero, dim3(1), dim3(64), 0, stream, cnt);

  const int nb = (n + BLK - 1) / BLK;
  hipLaunchKernelGGL(k_hist, dim3(nb), dim3(BLK), 0, stream, spc, n, cnt);
  hipLaunchKernelGGL(k_prefix, dim3(1), dim3(64), 0, stream, cnt, cnt2, csum);
  hipLaunchKernelGGL(k_compact, dim3(nb), dim3(BLK), 0, stream, spc, r, n, cnt2,
                     inv, fracs, toffA, perm);
  hipLaunchKernelGGL(k_table, dim3((4 * 1024 * 24 + 255) / 256), dim3(256), 0,
                     stream, tbl, wtbl);

  if (!direct) {
    hipLaunchKernelGGL(rb_mfma<false>, dim3(BX, 16), dim3(BLK), 0, stream, fracs,
                       toffA, wtbl, W1, W2, W3, W4, out, cnt, csum, perm, tmp16, n);
    hipLaunchKernelGGL(k_scatter, dim3((n + 63) / 64), dim3(256), 0, stream, tmp16,
                       inv, out, n);
  } else {
    hipLaunchKernelGGL(rb_mfma<true>, dim3(BX, 16), dim3(BLK), 0, stream, fracs,
                       toffA, wtbl, W1, W2, W3, W4, out, cnt, csum, perm, tmp16, n);
  }
}

// Round 11
// 153.570 us; speedup vs baseline: 1.2861x; 1.2861x over previous
//
#include <hip/hip_runtime.h>
#include <math.h>

// N_MAX_L = [22,19,16,13], offsets [0,22,41,57], N_TOTAL=70
// W1: (4,4,22,32)  W2/W3: (4,4,32,32)  W4: (4,4,32,22)
#define BLK 256
#define BX 128
#define TSL 24608  // padded per-l table slice: 1024*24 + 32 floats
#define ROWB 152   // unified tmp row bytes; per-l segment bases 0,48,88,120

typedef __attribute__((ext_vector_type(8))) short short8;
typedef __attribute__((ext_vector_type(4))) float f32x4;

union Frag {
  short8 s;
  unsigned int u[4];
};

// Cheap round-half-up bf16 pack of two f32 into one u32 (low = a).
// No NaN guard (network values are bounded); vs RNE differs only at exact
// ties (prob ~2^-16) by 1 ulp.
__device__ __forceinline__ unsigned int pack_pair(float a, float b) {
  const unsigned int ua = __float_as_uint(a) + 0x8000u;
  const unsigned int ub = __float_as_uint(b) + 0x8000u;
  return (ua >> 16) | (ub & 0xFFFF0000u);
}

// hi/lo split: hi = rounded bf16 pair, lo = rounded bf16 of residuals
__device__ __forceinline__ void split_pair(float a, float b, unsigned int& hi,
                                           unsigned int& lo) {
  hi = pack_pair(a, b);
  const float ra = a - __uint_as_float(hi << 16);
  const float rb = b - __uint_as_float(hi & 0xFFFF0000u);
  lo = pack_pair(ra, rb);
}

// minimal silu: x * rcp(1 + exp2(-x*log2e)) -> 5 inst, 2 transcendental
__device__ __forceinline__ f32x4 silu4(f32x4 v) {
#pragma unroll
  for (int i = 0; i < 4; i++) {
    const float e = __builtin_amdgcn_exp2f(v[i] * -1.44269504f);
    v[i] = v[i] * __builtin_amdgcn_rcpf(1.0f + e);
  }
  return v;
}

// ---------------- histogram / prefix / compaction (+table staging) ----------

__global__ void k_zero(int* __restrict__ cnt) {
  if (threadIdx.x < 4) cnt[threadIdx.x] = 0;
}

__global__ void __launch_bounds__(BLK) k_hist(const int* __restrict__ spc, int n,
                                              int* __restrict__ cnt) {
  __shared__ int h[4];
  if (threadIdx.x < 4) h[threadIdx.x] = 0;
  __syncthreads();
  const int i = blockIdx.x * BLK + threadIdx.x;
  if (i < n) atomicAdd(&h[spc[i]], 1);
  __syncthreads();
  if (threadIdx.x < 4) atomicAdd(&cnt[threadIdx.x], h[threadIdx.x]);
}

__global__ void k_prefix(const int* __restrict__ cnt, int* __restrict__ cnt2,
                         int* __restrict__ csum) {
  if (threadIdx.x == 0) {
    int a = 0;
#pragma unroll
    for (int s = 0; s < 4; s++) {
      csum[s] = a;
      cnt2[s] = a;
      a += cnt[s];
    }
  }
}

// blocks [0, nb): species compaction; blocks [nb, nb+384): padded table staging
__global__ void __launch_bounds__(BLK) k_compact(const int* __restrict__ spc,
                                                 const float* __restrict__ r, int n,
                                                 int nb, int* __restrict__ cnt2,
                                                 int* __restrict__ inv,
                                                 float* __restrict__ fracs,
                                                 int* __restrict__ toffA,
                                                 int* __restrict__ perm,
                                                 const float* __restrict__ tbl,
                                                 float* __restrict__ wt) {
  if (blockIdx.x >= nb) {
    const int t = (blockIdx.x - nb) * BLK + threadIdx.x;
    if (t < 4 * 1024 * 24) {
      const int l = t / (1024 * 24);
      const int rem = t - l * (1024 * 24);
      const int idx = rem / 24;
      const int j = rem - idx * 24;
      const int off = (l == 0) ? 0 : (l == 1) ? 22 : (l == 2) ? 41 : 57;
      const int nl = (l == 0) ? 22 : (l == 1) ? 19 : (l == 2) ? 16 : 13;
      const float v = (j < nl) ? tbl[idx * 70 + off + j] : 0.f;
      wt[l * TSL + idx * 24 + j] = v;
    }
    if (t < 4 * 32) {
      const int l = t >> 5, j = t & 31;
      wt[l * TSL + 1024 * 24 + j] = 0.f;
    }
    return;
  }

  __shared__ int wcnt[4][4];
  __shared__ int wbase[4][4];
  const int tid = threadIdx.x;
  const int i = blockIdx.x * BLK + tid;
  const int lane = tid & 63;
  const int w = tid >> 6;
  const int s = (i < n) ? spc[i] : -1;
  const float rr = (i < n) ? r[i] : 0.f;

  int rank = 0;
#pragma unroll
  for (int sp = 0; sp < 4; sp++) {
    unsigned long long m = __ballot(s == sp);
    if (lane == 0) wcnt[w][sp] = __popcll(m);
    if (s == sp) rank = __popcll(m & ((1ULL << lane) - 1ULL));
  }
  __syncthreads();
  if (tid < 4) {
    const int c0 = wcnt[0][tid], c1 = wcnt[1][tid], c2 = wcnt[2][tid], c3 = wcnt[3][tid];
    const int b = atomicAdd(&cnt2[tid], c0 + c1 + c2 + c3);
    wbase[0][tid] = b;
    wbase[1][tid] = b + c0;
    wbase[2][tid] = b + c0 + c1;
    wbase[3][tid] = b + c0 + c1 + c2;
  }
  __syncthreads();
  if (s >= 0) {
    const int sp = wbase[w][s] + rank;  // tight index = csum[s] + pos
    const float xi = rr * (1023.0f / 5.0f);
    int idx = (int)floorf(xi);
    idx = idx < 0 ? 0 : (idx > 1022 ? 1022 : idx);
    inv[i] = sp;
    fracs[sp] = xi - (float)idx;
    toffA[sp] = idx * 96;  // table row = 24 f32 = 96 B
    perm[sp] = i;          // only used by DIRECT fallback
  }
}

// ---------------- MFMA compute ----------------

__device__ __forceinline__ void layer_hl(const Frag* A, const Frag& bh,
                                         const Frag& bl, f32x4& d0, f32x4& d1) {
  f32x4 z = {0.f, 0.f, 0.f, 0.f};
  d0 = __builtin_amdgcn_mfma_f32_16x16x32_bf16(A[0].s, bl.s, z, 0, 0, 0);
  d0 = __builtin_amdgcn_mfma_f32_16x16x32_bf16(A[0].s, bh.s, d0, 0, 0, 0);
  d1 = __builtin_amdgcn_mfma_f32_16x16x32_bf16(A[1].s, bl.s, z, 0, 0, 0);
  d1 = __builtin_amdgcn_mfma_f32_16x16x32_bf16(A[1].s, bh.s, d1, 0, 0, 0);
}

__device__ __forceinline__ void layer_h(const Frag* A, const Frag& bh, f32x4& d0,
                                        f32x4& d1) {
  f32x4 z = {0.f, 0.f, 0.f, 0.f};
  d0 = __builtin_amdgcn_mfma_f32_16x16x32_bf16(A[0].s, bh.s, z, 0, 0, 0);
  d1 = __builtin_amdgcn_mfma_f32_16x16x32_bf16(A[1].s, bh.s, z, 0, 0, 0);
}

struct GD {
  f32x4 a0, a1, b0, b1;
  float frac;
  int e;
  int valid;
};

template <bool DIRECT>
__device__ __forceinline__ GD do_gather(const float* __restrict__ fracs,
                                        const int* __restrict__ toffA,
                                        const int* __restrict__ perm,
                                        const char* __restrict__ tbB, int sp0,
                                        int ei, int count) {
  GD gd;
  gd.valid = ei < count;
  const int spi = sp0 + (gd.valid ? ei : 0);
  gd.frac = fracs[spi];
  const int to = toffA[spi];
  if (DIRECT) gd.e = perm[spi]; else gd.e = 0;
  const char* p = tbB + to;
  gd.a0 = *(const f32x4*)(p);
  gd.a1 = *(const f32x4*)(p + 16);
  gd.b0 = *(const f32x4*)(p + 96);
  gd.b1 = *(const f32x4*)(p + 112);
  return gd;
}

template <int L, int NL, int OFF, bool DIRECT>
__device__ void body(const float* __restrict__ fracs, const int* __restrict__ toffA,
                     const float* __restrict__ wt, const float* __restrict__ W1,
                     const float* __restrict__ W2, const float* __restrict__ W3,
                     const float* __restrict__ W4, float* __restrict__ out,
                     const int* __restrict__ cnt, const int* __restrict__ csum,
                     const int* __restrict__ perm, char* __restrict__ tmpB) {
  const int s = blockIdx.y & 3;
  const int count = cnt[s];
  if (count == 0) return;
  const int sp0 = csum[s];

  const int lane = threadIdx.x & 63;
  const int w = threadIdx.x >> 6;
  const int c = lane & 15;  // edge column within tile
  const int g = lane >> 4;  // k-group

  const float* __restrict__ w1 = W1 + (size_t)(L * 4 + s) * (22 * 32);
  const float* __restrict__ w2 = W2 + (size_t)(L * 4 + s) * (32 * 32);
  const float* __restrict__ w3 = W3 + (size_t)(L * 4 + s) * (32 * 32);
  const float* __restrict__ w4 = W4 + (size_t)(L * 4 + s) * (32 * 22);

  // A-frags (bf16, hi only): W1 standard k=8g+d; W2/W3/W4 permuted
  // k'(g,d) = (d<4 ? 4g+d : 16+4g+d-4) so the previous layer's D-register
  // layout feeds the next MFMA directly (no transpose, no LDS).
  Frag A1[2], A2[2], A3[2], A4[2];
#pragma unroll
  for (int jt = 0; jt < 2; jt++) {
    const int j = jt * 16 + c;
#pragma unroll
    for (int p = 0; p < 4; p++) {
      const int k0 = 8 * g + 2 * p, k1 = k0 + 1;
      const float a = (k0 < NL) ? w1[k0 * 32 + j] : 0.f;
      const float b = (k1 < NL) ? w1[k1 * 32 + j] : 0.f;
      A1[jt].u[p] = pack_pair(a, b);
      const int kp0 = (p < 2) ? (4 * g + 2 * p) : (16 + 4 * g + 2 * (p - 2));
      const int kp1 = kp0 + 1;
      A2[jt].u[p] = pack_pair(w2[kp0 * 32 + j], w2[kp1 * 32 + j]);
      A3[jt].u[p] = pack_pair(w3[kp0 * 32 + j], w3[kp1 * 32 + j]);
      A4[jt].u[p] = pack_pair((j < NL) ? w4[kp0 * 22 + j] : 0.f,
                              (j < NL) ? w4[kp1 * 22 + j] : 0.f);
    }
  }

  const char* __restrict__ tbB = (const char*)(wt + L * TSL + 8 * g);
  constexpr int LBASE = (L == 0) ? 0 : (L == 1) ? 48 : (L == 2) ? 88 : 120;
  constexpr int G1 = (NL > 16) ? ((NL - 16 + 3) / 4) : 0;  // d1 store g-limit

  const int stride = gridDim.x * 64;
  int eb = blockIdx.x * 64 + w * 16;
  GD cur = do_gather<DIRECT>(fracs, toffA, perm, tbB, sp0, eb + c, count);

  for (; eb < count; eb += stride) {
    GD nxt = do_gather<DIRECT>(fracs, toffA, perm, tbB, sp0, eb + stride + c, count);

    // ---- layer-1 B frags (standard k = 8g+d; pads are zero), hi/lo split ----
    Frag bh, bl;
    {
      float x[8];
#pragma unroll
      for (int d = 0; d < 4; d++) {
        x[d] = cur.a0[d] + cur.frac * (cur.b0[d] - cur.a0[d]);
        x[d + 4] = cur.a1[d] + cur.frac * (cur.b1[d] - cur.a1[d]);
      }
      split_pair(x[0], x[1], bh.u[0], bl.u[0]);
      split_pair(x[2], x[3], bh.u[1], bl.u[1]);
      split_pair(x[4], x[5], bh.u[2], bl.u[2]);
      split_pair(x[6], x[7], bh.u[3], bl.u[3]);
    }

    f32x4 d0, d1;
    layer_hl(A1, bh, bl, d0, d1);

    // ---- transitions: silu -> bf16 repack (k'-mapping) -> next layer ----
#pragma unroll
    for (int t = 0; t < 3; t++) {
      d0 = silu4(d0);
      d1 = silu4(d1);
      bh.u[0] = pack_pair(d0[0], d0[1]);
      bh.u[1] = pack_pair(d0[2], d0[3]);
      bh.u[2] = pack_pair(d1[0], d1[1]);
      bh.u[3] = pack_pair(d1[2], d1[3]);
      if (t == 0) layer_h(A2, bh, d0, d1);
      else if (t == 1) layer_h(A3, bh, d0, d1);
      else layer_h(A4, bh, d0, d1);
    }

    if (!DIRECT) {
      // ---- dense bf16 epilogue into unified 152-B row, segment base LBASE ----
      if (cur.valid) {
        const size_t ro = (size_t)(sp0 + eb + c) * ROWB + LBASE;
        const unsigned int u0 = pack_pair(d0[0], d0[1]);
        const unsigned int u1 = pack_pair(d0[2], d0[3]);
        *(uint2*)(tmpB + ro + 8 * g) = make_uint2(u0, u1);
        if (g < G1) {
          const unsigned int u2 = pack_pair(d1[0], d1[1]);
          const unsigned int u3 = pack_pair(d1[2], d1[3]);
          *(uint2*)(tmpB + ro + 32 + 8 * g) = make_uint2(u2, u3);
        }
      }
    } else {
      // fallback: scattered f32 stores (ws too small for tmp)
      float* __restrict__ o = out + (size_t)cur.e * 70 + OFF;
#pragma unroll
      for (int i2 = 0; i2 < 4; i2++) {
        const int j0 = 4 * g + i2;
        if (cur.valid && j0 < NL) o[j0] = d0[i2];
        const int j1 = 16 + 4 * g + i2;
        if (cur.valid && j1 < NL) o[j1] = d1[i2];
      }
    }

    cur = nxt;
  }
}

template <bool DIRECT>
__global__ void __launch_bounds__(BLK) rb_mfma(const float* __restrict__ fracs,
                                               const int* __restrict__ toffA,
                                               const float* __restrict__ wt,
                                               const float* __restrict__ W1,
                                               const float* __restrict__ W2,
                                               const float* __restrict__ W3,
                                               const float* __restrict__ W4,
                                               float* __restrict__ out,
                                               const int* __restrict__ cnt,
                                               const int* __restrict__ csum,
                                               const int* __restrict__ perm,
                                               char* __restrict__ tmpB) {
  switch (blockIdx.y >> 2) {
    case 0: body<0, 22, 0, DIRECT>(fracs, toffA, wt, W1, W2, W3, W4, out, cnt, csum, perm, tmpB); break;
    case 1: body<1, 19, 22, DIRECT>(fracs, toffA, wt, W1, W2, W3, W4, out, cnt, csum, perm, tmpB); break;
    case 2: body<2, 16, 41, DIRECT>(fracs, toffA, wt, W1, W2, W3, W4, out, cnt, csum, perm, tmpB); break;
    default: body<3, 13, 57, DIRECT>(fracs, toffA, wt, W1, W2, W3, W4, out, cnt, csum, perm, tmpB); break;
  }
}

// ---------------- natural-order streaming scatter ----------------

__device__ __forceinline__ int foff(int f) {
  return (f < 22) ? 2 * f
       : (f < 41) ? 48 + 2 * (f - 22)
       : (f < 57) ? 88 + 2 * (f - 41)
                  : 120 + 2 * (f - 57);
}

__global__ void __launch_bounds__(256) k_scatter(const char* __restrict__ tmpB,
                                                 const int* __restrict__ inv,
                                                 float* __restrict__ out, int n) {
  __shared__ int sinv[64];
  const int i0 = blockIdx.x * 64;
  if (threadIdx.x < 64) {
    const int i = i0 + threadIdx.x;
    sinv[threadIdx.x] = (i < n) ? inv[i] : 0;
  }
  __syncthreads();
  // 64 edges x 35 float2 chunks; reads one contiguous 152-B row per edge
  for (int q = threadIdx.x; q < 64 * 35; q += 256) {
    const int il = q / 35;
    const int p = q - il * 35;
    const int i = i0 + il;
    if (i >= n) continue;
    const char* __restrict__ row = tmpB + (size_t)sinv[il] * ROWB;
    const int f0 = 2 * p;
    const unsigned int h0 = *(const unsigned short*)(row + foff(f0));
    const unsigned int h1 = *(const unsigned short*)(row + foff(f0 + 1));
    float2 v;
    v.x = __uint_as_float(h0 << 16);
    v.y = __uint_as_float(h1 << 16);
    *(float2*)(out + (size_t)i * 70 + f0) = v;
  }
}

extern "C" void kernel_launch(void* const* d_in, const int* in_sizes, int n_in,
                              void* d_out, int out_size, void* d_ws, size_t ws_size,
                              hipStream_t stream) {
  const float* r = (const float*)d_in[0];
  const int* spc = (const int*)d_in[1];
  const float* tbl = (const float*)d_in[2];
  const float* W1 = (const float*)d_in[3];
  const float* W2 = (const float*)d_in[4];
  const float* W3 = (const float*)d_in[5];
  const float* W4 = (const float*)d_in[6];
  float* out = (float*)d_out;
  const int n = in_sizes[0];

  int* cnt = (int*)d_ws;        // [0..3]
  int* cnt2 = cnt + 4;          // [4..7] atomic bases
  int* csum = cnt + 8;          // [8..11]
  int* inv = cnt + 64;          // n ints
  float* fracs = (float*)(inv + n);
  int* toffA = (int*)(fracs + n);
  int* perm = toffA + n;
  float* wtbl = (float*)(perm + n);
  char* tmpB = (char*)(wtbl + 4 * TSL);
  const size_t need = (size_t)(tmpB + (size_t)ROWB * n - (char*)d_ws);
  const bool direct = ws_size < need;

  hipLaunchKernelGGL(k_zero, dim3(1), dim3(64), 0, stream, cnt);

  const int nb = (n + BLK - 1) / BLK;
  hipLaunchKernelGGL(k_hist, dim3(nb), dim3(BLK), 0, stream, spc, n, cnt);
  hipLaunchKernelGGL(k_prefix, dim3(1), dim3(64), 0, stream, cnt, cnt2, csum);
  hipLaunchKernelGGL(k_compact, dim3(nb + 384), dim3(BLK), 0, stream, spc, r, n,
                     nb, cnt2, inv, fracs, toffA, perm, tbl, wtbl);

  if (!direct) {
    hipLaunchKernelGGL(rb_mfma<false>, dim3(BX, 16), dim3(BLK), 0, stream, fracs,
                       toffA, wtbl, W1, W2, W3, W4, out, cnt, csum, perm, tmpB);
    hipLaunchKernelGGL(k_scatter, dim3((n + 63) / 64), dim3(256), 0, stream, tmpB,
                       inv, out, n);
  } else {
    hipLaunchKernelGGL(rb_mfma<true>, dim3(BX, 16), dim3(BLK), 0, stream, fracs,
                       toffA, wtbl, W1, W2, W3, W4, out, cnt, csum, perm, tmpB);
  }
}

// Round 12
// 138.192 us; speedup vs baseline: 1.4292x; 1.1113x over previous
//
#include <hip/hip_runtime.h>
#include <math.h>

// N_MAX_L = [22,19,16,13], offsets [0,22,41,57], N_TOTAL=70
// W1: (4,4,22,32)  W2/W3: (4,4,32,32)  W4: (4,4,32,22)
#define BLK 256
#define BX 192
#define TSL 24608  // padded per-l table slice: 1024*24 + 32 floats

typedef __attribute__((ext_vector_type(8))) short short8;
typedef __attribute__((ext_vector_type(4))) float f32x4;

union Frag {
  short8 s;
  unsigned int u[4];
};

// Cheap round-half-up bf16 pack of two f32 into one u32 (low = a).
__device__ __forceinline__ unsigned int pack_pair(float a, float b) {
  const unsigned int ua = __float_as_uint(a) + 0x8000u;
  const unsigned int ub = __float_as_uint(b) + 0x8000u;
  return (ua >> 16) | (ub & 0xFFFF0000u);
}

// hi/lo split: hi = rounded bf16 pair, lo = rounded bf16 of residuals
__device__ __forceinline__ void split_pair(float a, float b, unsigned int& hi,
                                           unsigned int& lo) {
  hi = pack_pair(a, b);
  const float ra = a - __uint_as_float(hi << 16);
  const float rb = b - __uint_as_float(hi & 0xFFFF0000u);
  lo = pack_pair(ra, rb);
}

// minimal silu: x * rcp(1 + exp2(-x*log2e))
__device__ __forceinline__ f32x4 silu4(f32x4 v) {
#pragma unroll
  for (int i = 0; i < 4; i++) {
    const float e = __builtin_amdgcn_exp2f(v[i] * -1.44269504f);
    v[i] = v[i] * __builtin_amdgcn_rcpf(1.0f + e);
  }
  return v;
}

// ---------------- histogram / prefix / compaction (+table staging) ----------

__global__ void k_zero(int* __restrict__ cnt) {
  if (threadIdx.x < 4) cnt[threadIdx.x] = 0;
}

__global__ void __launch_bounds__(BLK) k_hist(const int* __restrict__ spc, int n,
                                              int* __restrict__ cnt) {
  __shared__ int h[4];
  if (threadIdx.x < 4) h[threadIdx.x] = 0;
  __syncthreads();
  const int i = blockIdx.x * BLK + threadIdx.x;
  if (i < n) atomicAdd(&h[spc[i]], 1);
  __syncthreads();
  if (threadIdx.x < 4) atomicAdd(&cnt[threadIdx.x], h[threadIdx.x]);
}

__global__ void k_prefix(const int* __restrict__ cnt, int* __restrict__ cnt2,
                         int* __restrict__ csum) {
  if (threadIdx.x == 0) {
    int a = 0;
#pragma unroll
    for (int s = 0; s < 4; s++) {
      csum[s] = a;
      cnt2[s] = a;
      a += cnt[s];
    }
  }
}

// blocks [0, nb): species compaction; blocks [nb, nb+384): padded table staging
__global__ void __launch_bounds__(BLK) k_compact(const int* __restrict__ spc,
                                                 const float* __restrict__ r, int n,
                                                 int nb, int* __restrict__ cnt2,
                                                 float* __restrict__ fracs,
                                                 int* __restrict__ toffA,
                                                 int* __restrict__ perm,
                                                 const float* __restrict__ tbl,
                                                 float* __restrict__ wt) {
  if (blockIdx.x >= nb) {
    const int t = (blockIdx.x - nb) * BLK + threadIdx.x;
    if (t < 4 * 1024 * 24) {
      const int l = t / (1024 * 24);
      const int rem = t - l * (1024 * 24);
      const int idx = rem / 24;
      const int j = rem - idx * 24;
      const int off = (l == 0) ? 0 : (l == 1) ? 22 : (l == 2) ? 41 : 57;
      const int nl = (l == 0) ? 22 : (l == 1) ? 19 : (l == 2) ? 16 : 13;
      const float v = (j < nl) ? tbl[idx * 70 + off + j] : 0.f;
      wt[l * TSL + idx * 24 + j] = v;
    }
    if (t < 4 * 32) {
      const int l = t >> 5, j = t & 31;
      wt[l * TSL + 1024 * 24 + j] = 0.f;
    }
    return;
  }

  __shared__ int wcnt[4][4];
  __shared__ int wbase[4][4];
  const int tid = threadIdx.x;
  const int i = blockIdx.x * BLK + tid;
  const int lane = tid & 63;
  const int w = tid >> 6;
  const int s = (i < n) ? spc[i] : -1;
  const float rr = (i < n) ? r[i] : 0.f;

  int rank = 0;
#pragma unroll
  for (int sp = 0; sp < 4; sp++) {
    unsigned long long m = __ballot(s == sp);
    if (lane == 0) wcnt[w][sp] = __popcll(m);
    if (s == sp) rank = __popcll(m & ((1ULL << lane) - 1ULL));
  }
  __syncthreads();
  if (tid < 4) {
    const int c0 = wcnt[0][tid], c1 = wcnt[1][tid], c2 = wcnt[2][tid], c3 = wcnt[3][tid];
    const int b = atomicAdd(&cnt2[tid], c0 + c1 + c2 + c3);
    wbase[0][tid] = b;
    wbase[1][tid] = b + c0;
    wbase[2][tid] = b + c0 + c1;
    wbase[3][tid] = b + c0 + c1 + c2;
  }
  __syncthreads();
  if (s >= 0) {
    const int sp = wbase[w][s] + rank;  // tight index = csum[s] + pos
    const float xi = rr * (1023.0f / 5.0f);
    int idx = (int)floorf(xi);
    idx = idx < 0 ? 0 : (idx > 1022 ? 1022 : idx);
    fracs[sp] = xi - (float)idx;
    toffA[sp] = idx * 96;  // table row = 24 f32 = 96 B
    perm[sp] = i;          // natural edge id (output row)
  }
}

// ---------------- fused MFMA compute (all 4 l per block) ----------------

__device__ __forceinline__ void layer_hl(const Frag* A, const Frag& bh,
                                         const Frag& bl, f32x4& d0, f32x4& d1) {
  f32x4 z = {0.f, 0.f, 0.f, 0.f};
  d0 = __builtin_amdgcn_mfma_f32_16x16x32_bf16(A[0].s, bl.s, z, 0, 0, 0);
  d0 = __builtin_amdgcn_mfma_f32_16x16x32_bf16(A[0].s, bh.s, d0, 0, 0, 0);
  d1 = __builtin_amdgcn_mfma_f32_16x16x32_bf16(A[1].s, bl.s, z, 0, 0, 0);
  d1 = __builtin_amdgcn_mfma_f32_16x16x32_bf16(A[1].s, bh.s, d1, 0, 0, 0);
}

__device__ __forceinline__ void layer_h(const Frag* A, const Frag& bh, f32x4& d0,
                                        f32x4& d1) {
  f32x4 z = {0.f, 0.f, 0.f, 0.f};
  d0 = __builtin_amdgcn_mfma_f32_16x16x32_bf16(A[0].s, bh.s, z, 0, 0, 0);
  d1 = __builtin_amdgcn_mfma_f32_16x16x32_bf16(A[1].s, bh.s, z, 0, 0, 0);
}

__device__ __forceinline__ void ldA(const unsigned int* __restrict__ wfr,
                                    int base256, int lane, Frag* A) {
#pragma unroll
  for (int jt = 0; jt < 2; jt++) {
    const uint4 v =
        reinterpret_cast<const uint4*>(wfr + ((base256 + jt) << 8))[lane];
    A[jt].u[0] = v.x;
    A[jt].u[1] = v.y;
    A[jt].u[2] = v.z;
    A[jt].u[3] = v.w;
  }
}

// One l's full 4-layer MLP for a 16-edge tile; result stored into the wave's
// LDS transpose tile at aligned sub-base OFFA (dwords). D1 = store d1 block.
template <int L, int OFFA, bool D1>
__device__ __forceinline__ void proc_l(const unsigned int* __restrict__ wfr,
                                       const float* __restrict__ wt, int toff,
                                       float frac, int g, int lane,
                                       float* __restrict__ xrow) {
  const char* p = (const char*)(wt + (size_t)L * TSL + 8 * g) + toff;
  const f32x4 a0 = *(const f32x4*)(p);
  const f32x4 a1 = *(const f32x4*)(p + 16);
  const f32x4 b0 = *(const f32x4*)(p + 96);
  const f32x4 b1 = *(const f32x4*)(p + 112);

  Frag A1[2], A2[2], A3[2], A4[2];
  ldA(wfr, (L * 4 + 0) * 2, lane, A1);
  ldA(wfr, (L * 4 + 1) * 2, lane, A2);
  ldA(wfr, (L * 4 + 2) * 2, lane, A3);
  ldA(wfr, (L * 4 + 3) * 2, lane, A4);

  float x[8];
#pragma unroll
  for (int d = 0; d < 4; d++) {
    x[d] = a0[d] + frac * (b0[d] - a0[d]);
    x[d + 4] = a1[d] + frac * (b1[d] - a1[d]);
  }
  Frag bh, bl;
  split_pair(x[0], x[1], bh.u[0], bl.u[0]);
  split_pair(x[2], x[3], bh.u[1], bl.u[1]);
  split_pair(x[4], x[5], bh.u[2], bl.u[2]);
  split_pair(x[6], x[7], bh.u[3], bl.u[3]);

  f32x4 d0, d1;
  layer_hl(A1, bh, bl, d0, d1);
#pragma unroll
  for (int t = 0; t < 3; t++) {
    d0 = silu4(d0);
    d1 = silu4(d1);
    bh.u[0] = pack_pair(d0[0], d0[1]);
    bh.u[1] = pack_pair(d0[2], d0[3]);
    bh.u[2] = pack_pair(d1[0], d1[1]);
    bh.u[3] = pack_pair(d1[2], d1[3]);
    if (t == 0) layer_h(A2, bh, d0, d1);
    else if (t == 1) layer_h(A3, bh, d0, d1);
    else layer_h(A4, bh, d0, d1);
  }

  // d0 = features 4g..4g+3, d1 = features 16+4g..19+4g of this l's range.
  // Overflow past NL lands in the next l's region (overwritten later) or row
  // pad; L2/L3 skip d1 (no valid features >= 16).
  *(f32x4*)(xrow + OFFA + 4 * g) = d0;
  if (D1) *(f32x4*)(xrow + OFFA + 16 + 4 * g) = d1;
}

__global__ void __launch_bounds__(BLK) rb_fused(
    const float* __restrict__ fracs, const int* __restrict__ toffA,
    const int* __restrict__ perm, const float* __restrict__ wt,
    const float* __restrict__ W1, const float* __restrict__ W2,
    const float* __restrict__ W3, const float* __restrict__ W4,
    float* __restrict__ out, const int* __restrict__ cnt,
    const int* __restrict__ csum) {
  __shared__ unsigned int wfr[8192];  // 32KB: packed A-frags, all 4 l, 4 mats
  __shared__ float xp[4][16 * 76];    // per-wave row-transpose tiles (19KB)
  __shared__ int eid[4][16];

  const int s = blockIdx.y;
  const int count = cnt[s];
  if (count == 0) return;
  const int sp0 = csum[s];

  // ---- build per-species weight frags in LDS (entry index == LDS index) ----
  {
    const int nlarr[4] = {22, 19, 16, 13};
    for (int e = threadIdx.x; e < 8192; e += BLK) {
      const int p = e & 3;
      const int lane = (e >> 2) & 63;
      const int jt = (e >> 8) & 1;
      const int m = (e >> 9) & 3;
      const int l = e >> 11;
      const int c = lane & 15, g = lane >> 4;
      const int j = jt * 16 + c;
      const int nl = nlarr[l];
      float a, b;
      if (m == 0) {
        const int k0 = 8 * g + 2 * p, k1 = k0 + 1;
        const float* wp = W1 + (size_t)(l * 4 + s) * 704;
        a = (k0 < nl) ? wp[k0 * 32 + j] : 0.f;
        b = (k1 < nl) ? wp[k1 * 32 + j] : 0.f;
      } else {
        const int kp0 = (p < 2) ? (4 * g + 2 * p) : (16 + 4 * g + 2 * (p - 2));
        const int kp1 = kp0 + 1;
        if (m == 1) {
          const float* wp = W2 + (size_t)(l * 4 + s) * 1024;
          a = wp[kp0 * 32 + j];
          b = wp[kp1 * 32 + j];
        } else if (m == 2) {
          const float* wp = W3 + (size_t)(l * 4 + s) * 1024;
          a = wp[kp0 * 32 + j];
          b = wp[kp1 * 32 + j];
        } else {
          const float* wp = W4 + (size_t)(l * 4 + s) * 704;
          a = (j < nl) ? wp[kp0 * 22 + j] : 0.f;
          b = (j < nl) ? wp[kp1 * 22 + j] : 0.f;
        }
      }
      wfr[e] = pack_pair(a, b);
    }
  }
  __syncthreads();

  const int lane = threadIdx.x & 63;
  const int w = threadIdx.x >> 6;
  const int c = lane & 15, g = lane >> 4;
  float* __restrict__ xpw = xp[w];
  int* __restrict__ eidw = eid[w];
  float* __restrict__ xrow = xpw + c * 76;
  const int stride = gridDim.x * 64;

  int eb = blockIdx.x * 64 + w * 16;
  int ei = eb + c;
  int valid = ei < count;
  int spi = sp0 + (valid ? ei : 0);
  float frac = fracs[spi];
  int toff = toffA[spi];
  int e0 = perm[spi];

  for (; eb < count; eb += stride) {
    // prefetch next tile's scalars (independent; overlaps compute)
    const int nei = eb + stride + c;
    const int nvalid = nei < count;
    const int nspi = sp0 + (nvalid ? nei : 0);
    const float nfrac = fracs[nspi];
    const int ntoff = toffA[nspi];
    const int ne = perm[nspi];

    proc_l<0, 0, true>(wfr, wt, toff, frac, g, lane, xrow);
    proc_l<1, 24, true>(wfr, wt, toff, frac, g, lane, xrow);
    proc_l<2, 44, false>(wfr, wt, toff, frac, g, lane, xrow);
    proc_l<3, 60, false>(wfr, wt, toff, frac, g, lane, xrow);

    if (g == 0) eidw[c] = valid ? e0 : -1;
    __asm__ volatile("" ::: "memory");

    // ---- write full 280-B rows: contiguous dwords per row, rows by perm ----
#pragma unroll
    for (int it = 0; it < 18; it++) {
      const int t = it * 64 + lane;
      if (t < 16 * 70) {
        const int row = t / 70;
        const int f = t - row * 70;
        const int er = eidw[row];
        const int fl = f + ((f >= 22) ? 2 : 0) + ((f >= 41) ? 1 : 0);
        if (er >= 0) out[(size_t)er * 70 + f] = xpw[row * 76 + fl];
      }
    }
    __asm__ volatile("" ::: "memory");

    frac = nfrac;
    toff = ntoff;
    e0 = ne;
    valid = nvalid;
  }
}

extern "C" void kernel_launch(void* const* d_in, const int* in_sizes, int n_in,
                              void* d_out, int out_size, void* d_ws, size_t ws_size,
                              hipStream_t stream) {
  const float* r = (const float*)d_in[0];
  const int* spc = (const int*)d_in[1];
  const float* tbl = (const float*)d_in[2];
  const float* W1 = (const float*)d_in[3];
  const float* W2 = (const float*)d_in[4];
  const float* W3 = (const float*)d_in[5];
  const float* W4 = (const float*)d_in[6];
  float* out = (float*)d_out;
  const int n = in_sizes[0];

  int* cnt = (int*)d_ws;   // [0..3]
  int* cnt2 = cnt + 4;     // [4..7] atomic bases
  int* csum = cnt + 8;     // [8..11]
  float* fracs = (float*)(cnt + 64);  // n floats
  int* toffA = (int*)(fracs + n);     // n ints
  int* perm = toffA + n;              // n ints
  float* wtbl = (float*)(perm + n);   // 4*TSL floats

  hipLaunchKernelGGL(k_zero, dim3(1), dim3(64), 0, stream, cnt);

  const int nb = (n + BLK - 1) / BLK;
  hipLaunchKernelGGL(k_hist, dim3(nb), dim3(BLK), 0, stream, spc, n, cnt);
  hipLaunchKernelGGL(k_prefix, dim3(1), dim3(64), 0, stream, cnt, cnt2, csum);
  hipLaunchKernelGGL(k_compact, dim3(nb + 384), dim3(BLK), 0, stream, spc, r, n,
                     nb, cnt2, fracs, toffA, perm, tbl, wtbl);

  hipLaunchKernelGGL(rb_fused, dim3(BX, 4), dim3(BLK), 0, stream, fracs, toffA,
                     perm, wtbl, W1, W2, W3, W4, out, cnt, csum);
}

// Round 13
// 127.699 us; speedup vs baseline: 1.5466x; 1.0822x over previous
//
#include <hip/hip_runtime.h>
#include <math.h>

// N_MAX_L = [22,19,16,13], offsets [0,22,41,57], N_TOTAL=70
// W1: (4,4,22,32)  W2/W3: (4,4,32,32)  W4: (4,4,32,22)
#define BLK 256
#define BX 128
#define NEDGE_MAX 400000
#define TSL 24608  // padded per-l table slice: 1024*24 + 32 floats

typedef __attribute__((ext_vector_type(8))) short short8;
typedef __attribute__((ext_vector_type(4))) float f32x4;

union Frag {
  short8 s;
  unsigned int u[4];
};

// Cheap round-half-up bf16 pack of two f32 into one u32 (low = a).
__device__ __forceinline__ unsigned int pack_pair(float a, float b) {
  const unsigned int ua = __float_as_uint(a) + 0x8000u;
  const unsigned int ub = __float_as_uint(b) + 0x8000u;
  return (ua >> 16) | (ub & 0xFFFF0000u);
}

// hi/lo split: hi = rounded bf16 pair, lo = rounded bf16 of residuals
__device__ __forceinline__ void split_pair(float a, float b, unsigned int& hi,
                                           unsigned int& lo) {
  hi = pack_pair(a, b);
  const float ra = a - __uint_as_float(hi << 16);
  const float rb = b - __uint_as_float(hi & 0xFFFF0000u);
  lo = pack_pair(ra, rb);
}

// minimal silu: x * rcp(1 + exp2(-x*log2e))
__device__ __forceinline__ f32x4 silu4(f32x4 v) {
#pragma unroll
  for (int i = 0; i < 4; i++) {
    const float e = __builtin_amdgcn_exp2f(v[i] * -1.44269504f);
    v[i] = v[i] * __builtin_amdgcn_rcpf(1.0f + e);
  }
  return v;
}

// ---------------- compaction (+table staging), round-8 style ----------------

__global__ void k_zero(int* __restrict__ cnt) {
  if (threadIdx.x < 4) cnt[threadIdx.x] = 0;
}

// blocks [0, nb): species compaction; blocks [nb, nb+384): padded table staging
__global__ void __launch_bounds__(BLK) k_compact(const int* __restrict__ spc,
                                                 const float* __restrict__ r, int n,
                                                 int nb, int* __restrict__ cnt,
                                                 float* __restrict__ fracs,
                                                 int* __restrict__ toffA,
                                                 int* __restrict__ perm,
                                                 const float* __restrict__ tbl,
                                                 float* __restrict__ wt) {
  if (blockIdx.x >= nb) {
    const int t = (blockIdx.x - nb) * BLK + threadIdx.x;
    if (t < 4 * 1024 * 24) {
      const int l = t / (1024 * 24);
      const int rem = t - l * (1024 * 24);
      const int idx = rem / 24;
      const int j = rem - idx * 24;
      const int off = (l == 0) ? 0 : (l == 1) ? 22 : (l == 2) ? 41 : 57;
      const int nl = (l == 0) ? 22 : (l == 1) ? 19 : (l == 2) ? 16 : 13;
      const float v = (j < nl) ? tbl[idx * 70 + off + j] : 0.f;
      wt[l * TSL + idx * 24 + j] = v;
    }
    if (t < 4 * 32) {
      const int l = t >> 5, j = t & 31;
      wt[l * TSL + 1024 * 24 + j] = 0.f;
    }
    return;
  }

  __shared__ int wcnt[4][4];
  __shared__ int wbase[4][4];
  const int tid = threadIdx.x;
  const int i = blockIdx.x * BLK + tid;
  const int lane = tid & 63;
  const int w = tid >> 6;
  const int s = (i < n) ? spc[i] : -1;
  const float rr = (i < n) ? r[i] : 0.f;

  int rank = 0;
#pragma unroll
  for (int sp = 0; sp < 4; sp++) {
    unsigned long long m = __ballot(s == sp);
    if (lane == 0) wcnt[w][sp] = __popcll(m);
    if (s == sp) rank = __popcll(m & ((1ULL << lane) - 1ULL));
  }
  __syncthreads();
  if (tid < 4) {
    const int c0 = wcnt[0][tid], c1 = wcnt[1][tid], c2 = wcnt[2][tid], c3 = wcnt[3][tid];
    const int b = atomicAdd(&cnt[tid], c0 + c1 + c2 + c3);
    wbase[0][tid] = b;
    wbase[1][tid] = b + c0;
    wbase[2][tid] = b + c0 + c1;
    wbase[3][tid] = b + c0 + c1 + c2;
  }
  __syncthreads();
  if (s >= 0) {
    const int pos = s * NEDGE_MAX + wbase[w][s] + rank;
    const float xi = rr * (1023.0f / 5.0f);
    int idx = (int)floorf(xi);
    idx = idx < 0 ? 0 : (idx > 1022 ? 1022 : idx);
    fracs[pos] = xi - (float)idx;
    toffA[pos] = idx * 96;  // table row = 24 f32 = 96 B
    perm[pos] = i;          // natural edge id (output row)
  }
}

// ---------------- fused MFMA compute (2 l's per block, weights in regs) -----

__device__ __forceinline__ void layer_hl(const Frag* A, const Frag& bh,
                                         const Frag& bl, f32x4& d0, f32x4& d1) {
  f32x4 z = {0.f, 0.f, 0.f, 0.f};
  d0 = __builtin_amdgcn_mfma_f32_16x16x32_bf16(A[0].s, bl.s, z, 0, 0, 0);
  d0 = __builtin_amdgcn_mfma_f32_16x16x32_bf16(A[0].s, bh.s, d0, 0, 0, 0);
  d1 = __builtin_amdgcn_mfma_f32_16x16x32_bf16(A[1].s, bl.s, z, 0, 0, 0);
  d1 = __builtin_amdgcn_mfma_f32_16x16x32_bf16(A[1].s, bh.s, d1, 0, 0, 0);
}

__device__ __forceinline__ void layer_h(const Frag* A, const Frag& bh, f32x4& d0,
                                        f32x4& d1) {
  f32x4 z = {0.f, 0.f, 0.f, 0.f};
  d0 = __builtin_amdgcn_mfma_f32_16x16x32_bf16(A[0].s, bh.s, z, 0, 0, 0);
  d1 = __builtin_amdgcn_mfma_f32_16x16x32_bf16(A[1].s, bh.s, z, 0, 0, 0);
}

// One l's 4-layer MLP for a 16-edge tile; d0 always stored at XBASE+4g,
// d1 stored for g<G1 at XBASE+16+4g. G1==0 also skips the final d1 MFMA.
template <int L, int NL, int XBASE, int G1>
__device__ __forceinline__ void proc_l(const Frag* A1, const Frag* A2,
                                       const Frag* A3, const Frag* A4,
                                       const float* __restrict__ wt, int toff,
                                       float frac, int g,
                                       float* __restrict__ xrow) {
  const char* p = (const char*)(wt + (size_t)L * TSL + 8 * g) + toff;
  const f32x4 a0 = *(const f32x4*)(p);
  const f32x4 a1 = *(const f32x4*)(p + 16);
  const f32x4 b0 = *(const f32x4*)(p + 96);
  const f32x4 b1 = *(const f32x4*)(p + 112);

  float x[8];
#pragma unroll
  for (int d = 0; d < 4; d++) {
    x[d] = a0[d] + frac * (b0[d] - a0[d]);
    x[d + 4] = a1[d] + frac * (b1[d] - a1[d]);
  }
  Frag bh, bl;
  split_pair(x[0], x[1], bh.u[0], bl.u[0]);
  split_pair(x[2], x[3], bh.u[1], bl.u[1]);
  split_pair(x[4], x[5], bh.u[2], bl.u[2]);
  split_pair(x[6], x[7], bh.u[3], bl.u[3]);

  f32x4 d0, d1;
  layer_hl(A1, bh, bl, d0, d1);

#pragma unroll
  for (int t = 0; t < 2; t++) {
    d0 = silu4(d0);
    d1 = silu4(d1);
    bh.u[0] = pack_pair(d0[0], d0[1]);
    bh.u[1] = pack_pair(d0[2], d0[3]);
    bh.u[2] = pack_pair(d1[0], d1[1]);
    bh.u[3] = pack_pair(d1[2], d1[3]);
    if (t == 0) layer_h(A2, bh, d0, d1);
    else layer_h(A3, bh, d0, d1);
  }
  d0 = silu4(d0);
  d1 = silu4(d1);
  bh.u[0] = pack_pair(d0[0], d0[1]);
  bh.u[1] = pack_pair(d0[2], d0[3]);
  bh.u[2] = pack_pair(d1[0], d1[1]);
  bh.u[3] = pack_pair(d1[2], d1[3]);
  f32x4 z = {0.f, 0.f, 0.f, 0.f};
  d0 = __builtin_amdgcn_mfma_f32_16x16x32_bf16(A4[0].s, bh.s, z, 0, 0, 0);
  if (G1 > 0) d1 = __builtin_amdgcn_mfma_f32_16x16x32_bf16(A4[1].s, bh.s, z, 0, 0, 0);

  *(f32x4*)(xrow + XBASE + 4 * g) = d0;
  if (g < G1) *(f32x4*)(xrow + XBASE + 16 + 4 * g) = d1;
}

// build one l's 4-matrix A-frag set into registers
template <int NL>
__device__ __forceinline__ void build_frags(const float* __restrict__ w1,
                                            const float* __restrict__ w2,
                                            const float* __restrict__ w3,
                                            const float* __restrict__ w4, int c,
                                            int g, Frag* A1, Frag* A2, Frag* A3,
                                            Frag* A4) {
#pragma unroll
  for (int jt = 0; jt < 2; jt++) {
    const int j = jt * 16 + c;
#pragma unroll
    for (int p = 0; p < 4; p++) {
      const int k0 = 8 * g + 2 * p, k1 = k0 + 1;
      const float a = (k0 < NL) ? w1[k0 * 32 + j] : 0.f;
      const float b = (k1 < NL) ? w1[k1 * 32 + j] : 0.f;
      A1[jt].u[p] = pack_pair(a, b);
      const int kp0 = (p < 2) ? (4 * g + 2 * p) : (16 + 4 * g + 2 * (p - 2));
      const int kp1 = kp0 + 1;
      A2[jt].u[p] = pack_pair(w2[kp0 * 32 + j], w2[kp1 * 32 + j]);
      A3[jt].u[p] = pack_pair(w3[kp0 * 32 + j], w3[kp1 * 32 + j]);
      A4[jt].u[p] = pack_pair((j < NL) ? w4[kp0 * 22 + j] : 0.f,
                              (j < NL) ? w4[kp1 * 22 + j] : 0.f);
    }
  }
}

template <int LP>
__device__ void fbody(const float* __restrict__ fracs,
                      const int* __restrict__ toffA, const int* __restrict__ perm,
                      const float* __restrict__ wt, const float* __restrict__ W1,
                      const float* __restrict__ W2, const float* __restrict__ W3,
                      const float* __restrict__ W4, float* __restrict__ out,
                      const int* __restrict__ cnt, float* __restrict__ xpw,
                      int* __restrict__ eidw) {
  constexpr int LA = 2 * LP, LB = 2 * LP + 1;
  constexpr int NLa = (LP == 0) ? 22 : 16;
  constexpr int NLb = (LP == 0) ? 19 : 13;
  constexpr int ROWD = (LP == 0) ? 44 : 36;  // xp row stride (dwords)
  constexpr int XBb = (LP == 0) ? 24 : 16;   // l_b sub-base in xp row
  constexpr int G1a = (LP == 0) ? 2 : 0;     // d1 store g-limit, l_a
  constexpr int G1b = (LP == 0) ? 1 : 0;     // d1 store g-limit, l_b
  constexpr int NDW = (LP == 0) ? 41 : 29;   // output dwords per row
  constexpr int FOFF = (LP == 0) ? 0 : 41;   // output feature offset

  const int s = blockIdx.y & 3;
  const int count = cnt[s];
  if (count == 0) return;
  const int sBase = s * NEDGE_MAX;

  const int lane = threadIdx.x & 63;
  const int w = threadIdx.x >> 6;
  const int c = lane & 15, g = lane >> 4;
  float* __restrict__ xrow = xpw + c * ROWD;

  Frag Aa1[2], Aa2[2], Aa3[2], Aa4[2], Ab1[2], Ab2[2], Ab3[2], Ab4[2];
  build_frags<NLa>(W1 + (size_t)(LA * 4 + s) * 704, W2 + (size_t)(LA * 4 + s) * 1024,
                   W3 + (size_t)(LA * 4 + s) * 1024, W4 + (size_t)(LA * 4 + s) * 704,
                   c, g, Aa1, Aa2, Aa3, Aa4);
  build_frags<NLb>(W1 + (size_t)(LB * 4 + s) * 704, W2 + (size_t)(LB * 4 + s) * 1024,
                   W3 + (size_t)(LB * 4 + s) * 1024, W4 + (size_t)(LB * 4 + s) * 704,
                   c, g, Ab1, Ab2, Ab3, Ab4);

  const int stride = gridDim.x * 64;
  int eb = blockIdx.x * 64 + w * 16;
  int valid = (eb + c) < count;
  int spi = sBase + (valid ? eb + c : 0);
  float frac = fracs[spi];
  int toff = toffA[spi];
  int e0 = perm[spi];

  for (; eb < count; eb += stride) {
    // prefetch next tile's scalars
    const int nei = eb + stride + c;
    const int nvalid = nei < count;
    const int nspi = sBase + (nvalid ? nei : 0);
    const float nfrac = fracs[nspi];
    const int ntoff = toffA[nspi];
    const int ne = perm[nspi];

    proc_l<LA, NLa, 0, G1a>(Aa1, Aa2, Aa3, Aa4, wt, toff, frac, g, xrow);
    proc_l<LB, NLb, XBb, G1b>(Ab1, Ab2, Ab3, Ab4, wt, toff, frac, g, xrow);

    if (g == 0) eidw[c] = valid ? e0 : -1;
    __asm__ volatile("" ::: "memory");

    // ---- contiguous segment stores: NDW dwords per row at out+er*70+FOFF ----
    constexpr int TOT = 16 * NDW;
#pragma unroll
    for (int it = 0; it < (TOT + 63) / 64; it++) {
      const int t = it * 64 + lane;
      if (t < TOT) {
        const int row = t / NDW;
        const int f0 = t - row * NDW;
        const int fl = (LP == 0) ? (f0 + ((f0 >= 22) ? 2 : 0)) : f0;
        const int er = eidw[row];
        if (er >= 0) out[(size_t)er * 70 + FOFF + f0] = xpw[row * ROWD + fl];
      }
    }
    __asm__ volatile("" ::: "memory");

    frac = nfrac;
    toff = ntoff;
    e0 = ne;
    valid = nvalid;
  }
}

__global__ void __launch_bounds__(BLK, 4) rb_fused(
    const float* __restrict__ fracs, const int* __restrict__ toffA,
    const int* __restrict__ perm, const float* __restrict__ wt,
    const float* __restrict__ W1, const float* __restrict__ W2,
    const float* __restrict__ W3, const float* __restrict__ W4,
    float* __restrict__ out, const int* __restrict__ cnt) {
  __shared__ float xp[4][16 * 44];
  __shared__ int eid[4][16];
  const int w = threadIdx.x >> 6;
  if ((blockIdx.y >> 2) == 0)
    fbody<0>(fracs, toffA, perm, wt, W1, W2, W3, W4, out, cnt, xp[w], eid[w]);
  else
    fbody<1>(fracs, toffA, perm, wt, W1, W2, W3, W4, out, cnt, xp[w], eid[w]);
}

extern "C" void kernel_launch(void* const* d_in, const int* in_sizes, int n_in,
                              void* d_out, int out_size, void* d_ws, size_t ws_size,
                              hipStream_t stream) {
  const float* r = (const float*)d_in[0];
  const int* spc = (const int*)d_in[1];
  const float* tbl = (const float*)d_in[2];
  const float* W1 = (const float*)d_in[3];
  const float* W2 = (const float*)d_in[4];
  const float* W3 = (const float*)d_in[5];
  const float* W4 = (const float*)d_in[6];
  float* out = (float*)d_out;
  const int n = in_sizes[0];

  int* cnt = (int*)d_ws;                       // 4 ints (+pad to 64)
  float* fracs = (float*)(cnt + 64);           // 4*NEDGE_MAX floats
  int* toffA = (int*)(fracs + 4 * NEDGE_MAX);  // 4*NEDGE_MAX ints
  int* perm = toffA + 4 * NEDGE_MAX;           // 4*NEDGE_MAX ints
  float* wtbl = (float*)(perm + 4 * NEDGE_MAX);  // 4*TSL floats

  hipLaunchKernelGGL(k_zero, dim3(1), dim3(64), 0, stream, cnt);

  const int nb = (n + BLK - 1) / BLK;
  hipLaunchKernelGGL(k_compact, dim3(nb + 384), dim3(BLK), 0, stream, spc, r, n,
                     nb, cnt, fracs, toffA, perm, tbl, wtbl);

  hipLaunchKernelGGL(rb_fused, dim3(BX, 8), dim3(BLK), 0, stream, fracs, toffA,
                     perm, wtbl, W1, W2, W3, W4, out, cnt);
}